// Round 8
// baseline (968.948 us; speedup 1.0000x reference)
//
#include <hip/hip_runtime.h>
#include <hip/hip_bf16.h>

typedef __bf16 bf16_t;
typedef __bf16 bf16x8 __attribute__((ext_vector_type(8)));
typedef __bf16 bf16x4 __attribute__((ext_vector_type(4)));
typedef float f32x4 __attribute__((ext_vector_type(4)));
typedef float f32x16 __attribute__((ext_vector_type(16)));

#define MFMA16(a, b, c) __builtin_amdgcn_mfma_f32_16x16x32_bf16((a), (b), (c), 0, 0, 0)
#define MFMA32(a, b, c) __builtin_amdgcn_mfma_f32_32x32x16_bf16((a), (b), (c), 0, 0, 0)

#define WN 393216  // elems per weight matrix (512*768)

// load 8 consecutive f32, round to bf16x8 (RNE)
__device__ inline bf16x8 cvt8(const float* __restrict__ p) {
    f32x4 a = *reinterpret_cast<const f32x4*>(p);
    f32x4 b = *reinterpret_cast<const f32x4*>(p + 4);
    bf16x8 r;
    r[0] = (bf16_t)a[0]; r[1] = (bf16_t)a[1]; r[2] = (bf16_t)a[2]; r[3] = (bf16_t)a[3];
    r[4] = (bf16_t)b[0]; r[5] = (bf16_t)b[1]; r[6] = (bf16_t)b[2]; r[7] = (bf16_t)b[3];
    return r;
}

// async global->LDS DMA, 16 B/lane; LDS dest = wave-uniform base + lane*16
__device__ __forceinline__ void gload_lds16(const bf16_t* g, bf16_t* l) {
    __builtin_amdgcn_global_load_lds(
        (const __attribute__((address_space(1))) void*)g,
        (__attribute__((address_space(3))) void*)l, 16, 0, 0);
}

// ---------------------------------------------------------------------------
// All 4 weight matrices f32 -> bf16 into contiguous ws block, one launch.
// ---------------------------------------------------------------------------
__global__ __launch_bounds__(256) void cvt_w4(
    const float* __restrict__ s0, const float* __restrict__ s1,
    const float* __restrict__ s2, const float* __restrict__ s3,
    bf16_t* __restrict__ d)
{
    int i = blockIdx.x * 256 + threadIdx.x;   // quad index; total 4*WN/4
    int seg = i / (WN / 4);
    int off = i - seg * (WN / 4);
    const float* s = (seg == 0) ? s0 : (seg == 1) ? s1 : (seg == 2) ? s2 : s3;
    f32x4 v = reinterpret_cast<const f32x4*>(s)[off];
    bf16x4 r;
    r[0] = (bf16_t)v[0]; r[1] = (bf16_t)v[1];
    r[2] = (bf16_t)v[2]; r[3] = (bf16_t)v[3];
    reinterpret_cast<bf16x4*>(d)[i] = r;
}

// ---------------------------------------------------------------------------
// Merged projection: all 4 linears in one grid of 32-row blocks.
//   id <  784 : visual_tokens -> o_ve (+bf16 mirror), L2 norm
//   id < 1040 : textual_tokens -> o_te (+mirror), L2 norm
//   id < 1044 : visual_cls -> o_vcls
//   else      : textual_cls -> o_tcls
// Block = 4 waves; wave w: cols w*128..+127 (8 col-tiles), 2 row-tiles of 16.
// 16x16x32 MFMA; C/D: row = quad*4+reg, col = lane&15 (HW-confirmed r3).
// ---------------------------------------------------------------------------
__global__ __launch_bounds__(256) void proj_all(
    const float* __restrict__ vtok, const float* __restrict__ ttok,
    const float* __restrict__ vcls, const float* __restrict__ tcls,
    const bf16_t* __restrict__ w_all,   // [4][512][768] bf16: Wv_cls|Wt_cls|Wv_tok|Wt_tok
    const float* __restrict__ bvc, const float* __restrict__ btc,
    const float* __restrict__ bvt, const float* __restrict__ btt,
    float* __restrict__ out_base,       // d_out f32
    bf16_t* __restrict__ bve, bf16_t* __restrict__ bte)
{
    const int tid  = threadIdx.x;
    const int wave = tid >> 6;
    const int lane = tid & 63;
    const int l16  = lane & 15;
    const int quad = lane >> 4;
    const int e0   = wave * 128;
    const int id   = blockIdx.x;

    const float* A; const bf16_t* W; const float* bias;
    float* out; bf16_t* outb; int do_l2, m0;
    if (id < 784)       { A = vtok; W = w_all + 2 * WN; bias = bvt;
                          out = out_base + 131072;   outb = bve; do_l2 = 1; m0 = id * 32; }
    else if (id < 1040) { A = ttok; W = w_all + 3 * WN; bias = btt;
                          out = out_base + 12976128; outb = bte; do_l2 = 1; m0 = (id - 784) * 32; }
    else if (id < 1044) { A = vcls; W = w_all;          bias = bvc;
                          out = out_base;             outb = nullptr; do_l2 = 0; m0 = (id - 1040) * 32; }
    else                { A = tcls; W = w_all + WN;     bias = btc;
                          out = out_base + 65536;     outb = nullptr; do_l2 = 0; m0 = (id - 1044) * 32; }

    f32x4 acc[2][8];
#pragma unroll
    for (int rt = 0; rt < 2; ++rt)
#pragma unroll
        for (int t = 0; t < 8; ++t) acc[rt][t] = (f32x4){0.f, 0.f, 0.f, 0.f};

    const float* ar0 = A + (size_t)(m0 + l16) * 768 + quad * 8;
    const float* ar1 = ar0 + (size_t)16 * 768;

    for (int k0 = 0; k0 < 768; k0 += 32) {
        bf16x8 a0 = cvt8(ar0 + k0);
        bf16x8 a1 = cvt8(ar1 + k0);
#pragma unroll
        for (int t = 0; t < 8; ++t) {
            bf16x8 wv = *reinterpret_cast<const bf16x8*>(
                W + (size_t)(e0 + t * 16 + l16) * 768 + quad * 8 + k0);
            acc[0][t] = MFMA16(a0, wv, acc[0][t]);
            acc[1][t] = MFMA16(a1, wv, acc[1][t]);
        }
    }

#pragma unroll
    for (int t = 0; t < 8; ++t) {
        float bv = bias[e0 + t * 16 + l16];
#pragma unroll
        for (int rt = 0; rt < 2; ++rt)
#pragma unroll
            for (int r = 0; r < 4; ++r) acc[rt][t][r] += bv;
    }

    float inv[2][4];
#pragma unroll
    for (int rt = 0; rt < 2; ++rt)
#pragma unroll
        for (int r = 0; r < 4; ++r) inv[rt][r] = 1.f;

    __shared__ float sq[4][32];
    if (do_l2) {
#pragma unroll
        for (int rt = 0; rt < 2; ++rt)
#pragma unroll
            for (int r = 0; r < 4; ++r) {
                float s = 0.f;
#pragma unroll
                for (int t = 0; t < 8; ++t) s += acc[rt][t][r] * acc[rt][t][r];
                s += __shfl_xor(s, 1);
                s += __shfl_xor(s, 2);
                s += __shfl_xor(s, 4);
                s += __shfl_xor(s, 8);
                if (l16 == 0) sq[wave][rt * 16 + quad * 4 + r] = s;
            }
        __syncthreads();
#pragma unroll
        for (int rt = 0; rt < 2; ++rt)
#pragma unroll
            for (int r = 0; r < 4; ++r) {
                int row = rt * 16 + quad * 4 + r;
                float tot = sq[0][row] + sq[1][row] + sq[2][row] + sq[3][row];
                inv[rt][r] = 1.0f / fmaxf(sqrtf(tot), 1e-12f);
            }
    }

#pragma unroll
    for (int rt = 0; rt < 2; ++rt)
#pragma unroll
        for (int t = 0; t < 8; ++t)
#pragma unroll
            for (int r = 0; r < 4; ++r) {
                const size_t o = (size_t)(m0 + rt * 16 + quad * 4 + r) * 512
                               + (e0 + t * 16 + l16);
                float val = acc[rt][t][r] * inv[rt][r];
                out[o] = val;
                if (outb) outb[o] = (bf16_t)val;
            }
}

// ---------------------------------------------------------------------------
// MaxSim v4: 32x32x16 MFMA. Block = (q, b-pair), XCD-swizzled so all 64
// b-blocks of a q land on one XCD (q = grp*8 + blockIdx%8).
// Wave (tt, vh): t rows tt*32..+31 for both b's; v-tiles vh ? {4,5,6} : {0..3}
// (224 staged rows, 196 valid). ve chunks (224 x 64k) via global_load_lds,
// double-buffered, XOR-swizzled (phys seg = logical ^ (row&7)).
// A/B layout: m|n = lane&31, k = (lane>>5)*8+j. C/D: col = lane&31,
// row = (reg&3) + 8*(reg>>2) + 4*(lane>>5).
// ---------------------------------------------------------------------------
__global__ __launch_bounds__(256) void maxsim32(
    const bf16_t* __restrict__ te,  // [128,64,512]
    const bf16_t* __restrict__ ve,  // [128,196,512]
    float* __restrict__ sim)        // [128,128] (b major)
{
    const int tid  = threadIdx.x;
    const int wave = tid >> 6;
    const int lane = tid & 63;
    const int l32  = lane & 31;
    const int h    = lane >> 5;
    const int tt   = wave & 1;
    const int vh   = wave >> 1;
    const int nt   = vh ? 3 : 4;
    const int vbase = vh * 4;

    const int n   = blockIdx.x;
    const int q   = (n >> 9) * 8 + (n & 7);   // 16 grps x 8 xcd
    const int bp  = (n >> 3) & 63;

    __shared__ bf16_t vs[2][224 * 64];        // 2 x 28672 B
    __shared__ float  tmax_s[2][2][64];       // [b][vh][t]
    __shared__ float  vmax_s[2][2][224];      // [b][tt][v]

    f32x16 acc[2][4];
#pragma unroll
    for (int bi = 0; bi < 2; ++bi)
#pragma unroll
        for (int vt = 0; vt < 4; ++vt)
#pragma unroll
            for (int r = 0; r < 16; ++r) acc[bi][vt][r] = 0.f;

    auto issue = [&](int buf, int c) {
        for (int g = wave; g < 28; g += 4) {      // 8 rows per DMA instr
            int r   = g * 8 + (lane >> 3);
            int sr  = r < 196 ? r : 195;          // clamp; excluded in reductions
            int seg = (lane & 7) ^ (lane >> 3);   // logical seg for phys slot l&7
            gload_lds16(ve + ((size_t)q * 196 + sr) * 512 + c * 64 + seg * 8,
                        &vs[buf][g * 512]);
        }
    };

    issue(0, 0);
#pragma unroll
    for (int c = 0; c < 8; ++c) {
        __syncthreads();                          // buf c&1 DMA complete
        if (c < 7) issue((c + 1) & 1, c + 1);
        // te A-frags: t = tt*32 + l32, k = c*64 + ks*16 + h*8
        bf16x8 a[2][4];
#pragma unroll
        for (int bi = 0; bi < 2; ++bi)
#pragma unroll
            for (int ks = 0; ks < 4; ++ks)
                a[bi][ks] = *reinterpret_cast<const bf16x8*>(
                    te + ((size_t)(bp * 2 + bi) * 64 + tt * 32 + l32) * 512
                       + c * 64 + ks * 16 + h * 8);
        const int buf = c & 1;
#pragma unroll
        for (int ks = 0; ks < 4; ++ks)
#pragma unroll
            for (int vt = 0; vt < 4; ++vt) {
                if (vt < nt) {
                    int row  = (vbase + vt) * 32 + l32;
                    int phys = (ks * 2 + h) ^ (row & 7);
                    bf16x8 bv = *reinterpret_cast<const bf16x8*>(
                        &vs[buf][row * 64 + phys * 8]);
                    acc[0][vt] = MFMA32(a[0][ks], bv, acc[0][vt]);
                    acc[1][vt] = MFMA32(a[1][ks], bv, acc[1][vt]);
                }
            }
    }

    // ---- reductions. D map: col v = (vbase+vt)*32 + l32,
    //      row t(within tile) = (reg&3) + 8*(reg>>2) + 4*h.
#pragma unroll
    for (int bi = 0; bi < 2; ++bi) {
        // t2v partial: per t-row max over this wave's v range
        float rm[16];
#pragma unroll
        for (int reg = 0; reg < 16; ++reg) {
            float m = -3.0e38f;
#pragma unroll
            for (int vt = 0; vt < 4; ++vt) {
                int v = (vbase + vt) * 32 + l32;
                if (vt < nt && v < 196) m = fmaxf(m, acc[bi][vt][reg]);
            }
            m = fmaxf(m, __shfl_xor(m, 1));
            m = fmaxf(m, __shfl_xor(m, 2));
            m = fmaxf(m, __shfl_xor(m, 4));
            m = fmaxf(m, __shfl_xor(m, 8));
            m = fmaxf(m, __shfl_xor(m, 16));
            rm[reg] = m;
        }
        if (l32 == 0) {
#pragma unroll
            for (int reg = 0; reg < 16; ++reg) {
                int row = (reg & 3) + 8 * (reg >> 2) + 4 * h;
                tmax_s[bi][vh][tt * 32 + row] = rm[reg];
            }
        }
        // v2t partial: per v max over this wave's 32 t rows
#pragma unroll
        for (int vt = 0; vt < 4; ++vt) {
            if (vt < nt) {
                float m = acc[bi][vt][0];
#pragma unroll
                for (int reg = 1; reg < 16; ++reg) m = fmaxf(m, acc[bi][vt][reg]);
                m = fmaxf(m, __shfl_xor(m, 32));
                if (h == 0) vmax_s[bi][tt][(vbase + vt) * 32 + l32] = m;
            }
        }
    }
    __syncthreads();

    if (wave == 0) {
        float t0 = fmaxf(tmax_s[0][0][lane], tmax_s[0][1][lane]);
        float t1 = fmaxf(tmax_s[1][0][lane], tmax_s[1][1][lane]);
        float c0 = 0.f, c1 = 0.f;
        for (int v = lane; v < 196; v += 64) {
            c0 += fmaxf(vmax_s[0][0][v], vmax_s[0][1][v]);
            c1 += fmaxf(vmax_s[1][0][v], vmax_s[1][1][v]);
        }
#pragma unroll
        for (int mk = 1; mk <= 32; mk <<= 1) {
            t0 += __shfl_xor(t0, mk);
            t1 += __shfl_xor(t1, mk);
            c0 += __shfl_xor(c0, mk);
            c1 += __shfl_xor(c1, mk);
        }
        if (lane == 0) {
            sim[(size_t)(bp * 2 + 0) * 128 + q] = 0.5f * (t0 * (1.0f / 196.0f) + c0 * (1.0f / 64.0f));
            sim[(size_t)(bp * 2 + 1) * 128 + q] = 0.5f * (t1 * (1.0f / 196.0f) + c1 * (1.0f / 64.0f));
        }
    }
}

// ---------------------------------------------------------------------------
// Fallback projection (f32 weights, 64-row blocks) — used only if ws too small
// ---------------------------------------------------------------------------
__global__ __launch_bounds__(256) void proj_fb(
    const float* __restrict__ A, const float* __restrict__ Wf,
    const float* __restrict__ bias, float* __restrict__ out, int do_l2)
{
    const int tid  = threadIdx.x;
    const int wave = tid >> 6;
    const int lane = tid & 63;
    const int l16  = lane & 15;
    const int quad = lane >> 4;
    const int m0   = blockIdx.x * 16;
    const int e0   = wave * 128;

    f32x4 acc[8];
#pragma unroll
    for (int t = 0; t < 8; ++t) acc[t] = (f32x4){0.f, 0.f, 0.f, 0.f};
    const float* arow = A + (size_t)(m0 + l16) * 768 + quad * 8;
    for (int k0 = 0; k0 < 768; k0 += 32) {
        bf16x8 af = cvt8(arow + k0);
#pragma unroll
        for (int t = 0; t < 8; ++t) {
            bf16x8 wv = cvt8(Wf + (size_t)(e0 + t * 16 + l16) * 768 + quad * 8 + k0);
            acc[t] = MFMA16(af, wv, acc[t]);
        }
    }
#pragma unroll
    for (int t = 0; t < 8; ++t) {
        float bv = bias[e0 + t * 16 + l16];
#pragma unroll
        for (int r = 0; r < 4; ++r) acc[t][r] += bv;
    }
    float inv[4] = {1.f, 1.f, 1.f, 1.f};
    __shared__ float sq[4][16];
    if (do_l2) {
#pragma unroll
        for (int r = 0; r < 4; ++r) {
            float s = 0.f;
#pragma unroll
            for (int t = 0; t < 8; ++t) s += acc[t][r] * acc[t][r];
            s += __shfl_xor(s, 1); s += __shfl_xor(s, 2);
            s += __shfl_xor(s, 4); s += __shfl_xor(s, 8);
            if (l16 == 0) sq[wave][quad * 4 + r] = s;
        }
        __syncthreads();
#pragma unroll
        for (int r = 0; r < 4; ++r) {
            float tot = sq[0][quad * 4 + r] + sq[1][quad * 4 + r]
                      + sq[2][quad * 4 + r] + sq[3][quad * 4 + r];
            inv[r] = 1.0f / fmaxf(sqrtf(tot), 1e-12f);
        }
    }
#pragma unroll
    for (int t = 0; t < 8; ++t)
#pragma unroll
        for (int r = 0; r < 4; ++r)
            out[(size_t)(m0 + quad * 4 + r) * 512 + (e0 + t * 16 + l16)] =
                acc[t][r] * inv[r];
}

// ---------------------------------------------------------------------------
// Fallback maxsim (f32 operands from d_out, 16x16 path) — ws-too-small only
// ---------------------------------------------------------------------------
__global__ __launch_bounds__(256) void maxsim_fb(
    const float* __restrict__ te, const float* __restrict__ ve,
    float* __restrict__ sim)
{
    const int tid  = threadIdx.x;
    const int wave = tid >> 6;
    const int lane = tid & 63;
    const int l16  = lane & 15;
    const int quad = lane >> 4;
    const int q    = blockIdx.x >> 6;
    const int bp   = blockIdx.x & 63;

    __shared__ bf16_t vsl[208 * 72];
    __shared__ float  maxt_s[2][4][208];
    __shared__ float  t2v_part[2][4];

    f32x4 acc0[13], acc1[13];
#pragma unroll
    for (int vt = 0; vt < 13; ++vt) {
        acc0[vt] = (f32x4){0.f, 0.f, 0.f, 0.f};
        acc1[vt] = (f32x4){0.f, 0.f, 0.f, 0.f};
    }
    const size_t toff0 = ((size_t)(bp * 2) * 64 + wave * 16 + l16) * 512 + quad * 8;
    const size_t toff1 = toff0 + (size_t)64 * 512;

    for (int k0 = 0; k0 < 512; k0 += 64) {
        __syncthreads();
        for (int s = tid; s < 416; s += 256) {
            const int row  = s >> 1;
            const int half = s & 1;
            const int vsrc = row < 196 ? row : 195;
            bf16x8 tmp[4];
            const size_t goff = ((size_t)q * 196 + vsrc) * 512 + k0 + half * 32;
#pragma unroll
            for (int j = 0; j < 4; ++j) tmp[j] = cvt8(ve + goff + j * 8);
            bf16_t* dst = &vsl[row * 72 + half * 32];
#pragma unroll
            for (int j = 0; j < 4; ++j)
                *reinterpret_cast<bf16x8*>(dst + j * 8) = tmp[j];
        }
        __syncthreads();
#pragma unroll
        for (int ks = 0; ks < 2; ++ks) {
            bf16x8 a0 = cvt8(te + toff0 + k0 + ks * 32);
            bf16x8 a1 = cvt8(te + toff1 + k0 + ks * 32);
#pragma unroll
            for (int vt = 0; vt < 13; ++vt) {
                bf16x8 bv = *reinterpret_cast<const bf16x8*>(
                    &vsl[(vt * 16 + l16) * 72 + ks * 32 + quad * 8]);
                acc0[vt] = MFMA16(a0, bv, acc0[vt]);
                acc1[vt] = MFMA16(a1, bv, acc1[vt]);
            }
        }
    }
#pragma unroll
    for (int bi = 0; bi < 2; ++bi) {
        const f32x4* acc = bi ? acc1 : acc0;
        float sum_maxv = 0.f;
#pragma unroll
        for (int r = 0; r < 4; ++r) {
            float m = -3.0e38f;
#pragma unroll
            for (int vt = 0; vt < 13; ++vt) {
                int v = vt * 16 + l16;
                if (v < 196) m = fmaxf(m, acc[vt][r]);
            }
            m = fmaxf(m, __shfl_xor(m, 1));
            m = fmaxf(m, __shfl_xor(m, 2));
            m = fmaxf(m, __shfl_xor(m, 4));
            m = fmaxf(m, __shfl_xor(m, 8));
            sum_maxv += m;
        }
        sum_maxv += __shfl_xor(sum_maxv, 16);
        sum_maxv += __shfl_xor(sum_maxv, 32);
        if (lane == 0) t2v_part[bi][wave] = sum_maxv;
#pragma unroll
        for (int vt = 0; vt < 13; ++vt) {
            float m = fmaxf(fmaxf(acc[vt][0], acc[vt][1]),
                            fmaxf(acc[vt][2], acc[vt][3]));
            m = fmaxf(m, __shfl_xor(m, 16));
            m = fmaxf(m, __shfl_xor(m, 32));
            if (lane < 16) maxt_s[bi][wave][vt * 16 + l16] = m;
        }
    }
    __syncthreads();
    if (wave == 0) {
#pragma unroll
        for (int bi = 0; bi < 2; ++bi) {
            float s_row = t2v_part[bi][0] + t2v_part[bi][1]
                        + t2v_part[bi][2] + t2v_part[bi][3];
            float s_col = 0.f;
            for (int v = lane; v < 196; v += 64) {
                float m = fmaxf(fmaxf(maxt_s[bi][0][v], maxt_s[bi][1][v]),
                                fmaxf(maxt_s[bi][2][v], maxt_s[bi][3][v]));
                s_col += m;
            }
            s_col += __shfl_xor(s_col, 1);
            s_col += __shfl_xor(s_col, 2);
            s_col += __shfl_xor(s_col, 4);
            s_col += __shfl_xor(s_col, 8);
            s_col += __shfl_xor(s_col, 16);
            s_col += __shfl_xor(s_col, 32);
            if (lane == 0)
                sim[(size_t)(bp * 2 + bi) * 128 + q] =
                    0.5f * (s_row * (1.0f / 196.0f) + s_col * (1.0f / 64.0f));
        }
    }
}

// ---------------------------------------------------------------------------
// text_mask[b,t] = (t < len[b]); int64-vs-int32 auto-detect (lengths 1..64).
// ---------------------------------------------------------------------------
__global__ void mask_kernel(const int* __restrict__ len, float* __restrict__ mask)
{
    int i = blockIdx.x * 256 + threadIdx.x;
    int is64 = (len[1] == 0) ? 1 : 0;
    if (i < 128 * 64) {
        int b = i >> 6;
        int t = i & 63;
        int L = is64 ? len[2 * b] : len[b];
        mask[i] = (t < L) ? 1.0f : 0.0f;
    }
}

extern "C" void kernel_launch(void* const* d_in, const int* in_sizes, int n_in,
                              void* d_out, int out_size, void* d_ws, size_t ws_size,
                              hipStream_t stream)
{
    int idx[13] = {0, 1, 2, 3, 4, 5, 6, 7, 8, 9, 10, 11, 12};
    if (in_sizes && n_in >= 13) {
        bool dict = (in_sizes[2] == 19267584) && (in_sizes[4] == 393216);
        if (!dict) {
            static const int alpha_sizes[13] = {393216, 393216, 393216, 393216,
                                                512, 512, 512, 512, 128,
                                                98304, 6291456, 98304, 19267584};
            bool alpha = true;
            for (int i = 0; i < 13; ++i)
                if (in_sizes[i] != alpha_sizes[i]) { alpha = false; break; }
            if (alpha) {
                const int m[13] = {11, 9, 12, 10, 2, 6, 0, 4, 3, 7, 1, 5, 8};
                for (int i = 0; i < 13; ++i) idx[i] = m[i];
            }
        }
    }

    const float* visual_cls     = (const float*)d_in[idx[0]];
    const float* textual_cls    = (const float*)d_in[idx[1]];
    const float* visual_tokens  = (const float*)d_in[idx[2]];
    const float* textual_tokens = (const float*)d_in[idx[3]];
    const float* Wv_cls = (const float*)d_in[idx[4]];
    const float* bv_cls = (const float*)d_in[idx[5]];
    const float* Wt_cls = (const float*)d_in[idx[6]];
    const float* bt_cls = (const float*)d_in[idx[7]];
    const float* Wv_tok = (const float*)d_in[idx[8]];
    const float* bv_tok = (const float*)d_in[idx[9]];
    const float* Wt_tok = (const float*)d_in[idx[10]];
    const float* bt_tok = (const float*)d_in[idx[11]];
    const int*   text_length = (const int*)d_in[idx[12]];

    float* out    = (float*)d_out;
    float* o_vcls = out;
    float* o_tcls = out + 65536;
    float* o_ve   = out + 131072;
    float* o_te   = out + 12976128;
    float* o_mask = out + 17170432;
    float* o_sim  = out + 17178624;

    const size_t NVE = 12845056;
    const size_t NTE = 4194304;
    const bool ws_big = ws_size >= (4 * (size_t)WN + NVE + NTE) * 2;

    bf16_t* w_all = (bf16_t*)d_ws;            // 4 weights contiguous
    bf16_t* b_ve  = w_all + 4 * (size_t)WN;
    bf16_t* b_te  = b_ve + NVE;

    dim3 blk(256);
    if (ws_big) {
        cvt_w4<<<(4 * WN / 4 + 255) / 256, blk, 0, stream>>>(Wv_cls, Wt_cls, Wv_tok, Wt_tok, w_all);
        proj_all<<<1048, blk, 0, stream>>>(visual_tokens, textual_tokens,
                                           visual_cls, textual_cls, w_all,
                                           bv_cls, bt_cls, bv_tok, bt_tok,
                                           out, b_ve, b_te);
        mask_kernel<<<32, blk, 0, stream>>>(text_length, o_mask);
        maxsim32<<<128 * 64, blk, 0, stream>>>(b_te, b_ve, o_sim);
    } else {
        proj_fb<<<8,    blk, 0, stream>>>(visual_cls,     Wv_cls, bv_cls, o_vcls, 0);
        proj_fb<<<8,    blk, 0, stream>>>(textual_cls,    Wt_cls, bt_cls, o_tcls, 0);
        proj_fb<<<1568, blk, 0, stream>>>(visual_tokens,  Wv_tok, bv_tok, o_ve, 1);
        proj_fb<<<512,  blk, 0, stream>>>(textual_tokens, Wt_tok, bt_tok, o_te, 1);
        mask_kernel<<<32, blk, 0, stream>>>(text_length, o_mask);
        maxsim_fb<<<128 * 64, blk, 0, stream>>>(o_te, o_ve, o_sim);
    }
}

// Round 9
// 635.551 us; speedup vs baseline: 1.5246x; 1.5246x over previous
//
#include <hip/hip_runtime.h>
#include <hip/hip_bf16.h>

typedef __bf16 bf16_t;
typedef __bf16 bf16x8 __attribute__((ext_vector_type(8)));
typedef __bf16 bf16x4 __attribute__((ext_vector_type(4)));
typedef float f32x4 __attribute__((ext_vector_type(4)));
typedef float f32x16 __attribute__((ext_vector_type(16)));

#define MFMA16(a, b, c) __builtin_amdgcn_mfma_f32_16x16x32_bf16((a), (b), (c), 0, 0, 0)
#define MFMA32(a, b, c) __builtin_amdgcn_mfma_f32_32x32x16_bf16((a), (b), (c), 0, 0, 0)

#define WN 393216  // elems per weight matrix (512*768)

// load 8 consecutive f32, round to bf16x8 (RNE)
__device__ inline bf16x8 cvt8(const float* __restrict__ p) {
    f32x4 a = *reinterpret_cast<const f32x4*>(p);
    f32x4 b = *reinterpret_cast<const f32x4*>(p + 4);
    bf16x8 r;
    r[0] = (bf16_t)a[0]; r[1] = (bf16_t)a[1]; r[2] = (bf16_t)a[2]; r[3] = (bf16_t)a[3];
    r[4] = (bf16_t)b[0]; r[5] = (bf16_t)b[1]; r[6] = (bf16_t)b[2]; r[7] = (bf16_t)b[3];
    return r;
}

// async global->LDS DMA, 16 B/lane; LDS dest = wave-uniform base + lane*16
__device__ __forceinline__ void gload_lds16(const bf16_t* g, bf16_t* l) {
    __builtin_amdgcn_global_load_lds(
        (const __attribute__((address_space(1))) void*)g,
        (__attribute__((address_space(3))) void*)l, 16, 0, 0);
}

// ---------------------------------------------------------------------------
// All 4 weight matrices f32 -> bf16 into contiguous ws block, one launch.
// ---------------------------------------------------------------------------
__global__ __launch_bounds__(256) void cvt_w4(
    const float* __restrict__ s0, const float* __restrict__ s1,
    const float* __restrict__ s2, const float* __restrict__ s3,
    bf16_t* __restrict__ d)
{
    int i = blockIdx.x * 256 + threadIdx.x;   // quad index; total 4*WN/4
    int seg = i / (WN / 4);
    int off = i - seg * (WN / 4);
    const float* s = (seg == 0) ? s0 : (seg == 1) ? s1 : (seg == 2) ? s2 : s3;
    f32x4 v = reinterpret_cast<const f32x4*>(s)[off];
    bf16x4 r;
    r[0] = (bf16_t)v[0]; r[1] = (bf16_t)v[1];
    r[2] = (bf16_t)v[2]; r[3] = (bf16_t)v[3];
    reinterpret_cast<bf16x4*>(d)[i] = r;
}

// ---------------------------------------------------------------------------
// Merged projection: all 4 linears in one grid of 32-row blocks.
//   id <  784 : visual_tokens -> o_ve (+bf16 mirror), L2 norm
//   id < 1040 : textual_tokens -> o_te (+mirror), L2 norm
//   id < 1044 : visual_cls -> o_vcls
//   else      : textual_cls -> o_tcls
// Block = 4 waves; wave w: cols w*128..+127 (8 col-tiles), 2 row-tiles of 16.
// 16x16x32 MFMA; C/D: row = quad*4+reg, col = lane&15 (HW-confirmed r3).
// ---------------------------------------------------------------------------
__global__ __launch_bounds__(256) void proj_all(
    const float* __restrict__ vtok, const float* __restrict__ ttok,
    const float* __restrict__ vcls, const float* __restrict__ tcls,
    const bf16_t* __restrict__ w_all,   // [4][512][768] bf16: Wv_cls|Wt_cls|Wv_tok|Wt_tok
    const float* __restrict__ bvc, const float* __restrict__ btc,
    const float* __restrict__ bvt, const float* __restrict__ btt,
    float* __restrict__ out_base,       // d_out f32
    bf16_t* __restrict__ bve, bf16_t* __restrict__ bte)
{
    const int tid  = threadIdx.x;
    const int wave = tid >> 6;
    const int lane = tid & 63;
    const int l16  = lane & 15;
    const int quad = lane >> 4;
    const int e0   = wave * 128;
    const int id   = blockIdx.x;

    const float* A; const bf16_t* W; const float* bias;
    float* out; bf16_t* outb; int do_l2, m0;
    if (id < 784)       { A = vtok; W = w_all + 2 * WN; bias = bvt;
                          out = out_base + 131072;   outb = bve; do_l2 = 1; m0 = id * 32; }
    else if (id < 1040) { A = ttok; W = w_all + 3 * WN; bias = btt;
                          out = out_base + 12976128; outb = bte; do_l2 = 1; m0 = (id - 784) * 32; }
    else if (id < 1044) { A = vcls; W = w_all;          bias = bvc;
                          out = out_base;             outb = nullptr; do_l2 = 0; m0 = (id - 1040) * 32; }
    else                { A = tcls; W = w_all + WN;     bias = btc;
                          out = out_base + 65536;     outb = nullptr; do_l2 = 0; m0 = (id - 1044) * 32; }

    f32x4 acc[2][8];
#pragma unroll
    for (int rt = 0; rt < 2; ++rt)
#pragma unroll
        for (int t = 0; t < 8; ++t) acc[rt][t] = (f32x4){0.f, 0.f, 0.f, 0.f};

    const float* ar0 = A + (size_t)(m0 + l16) * 768 + quad * 8;
    const float* ar1 = ar0 + (size_t)16 * 768;

    for (int k0 = 0; k0 < 768; k0 += 32) {
        bf16x8 a0 = cvt8(ar0 + k0);
        bf16x8 a1 = cvt8(ar1 + k0);
#pragma unroll
        for (int t = 0; t < 8; ++t) {
            bf16x8 wv = *reinterpret_cast<const bf16x8*>(
                W + (size_t)(e0 + t * 16 + l16) * 768 + quad * 8 + k0);
            acc[0][t] = MFMA16(a0, wv, acc[0][t]);
            acc[1][t] = MFMA16(a1, wv, acc[1][t]);
        }
    }

#pragma unroll
    for (int t = 0; t < 8; ++t) {
        float bv = bias[e0 + t * 16 + l16];
#pragma unroll
        for (int rt = 0; rt < 2; ++rt)
#pragma unroll
            for (int r = 0; r < 4; ++r) acc[rt][t][r] += bv;
    }

    float inv[2][4];
#pragma unroll
    for (int rt = 0; rt < 2; ++rt)
#pragma unroll
        for (int r = 0; r < 4; ++r) inv[rt][r] = 1.f;

    __shared__ float sq[4][32];
    if (do_l2) {
#pragma unroll
        for (int rt = 0; rt < 2; ++rt)
#pragma unroll
            for (int r = 0; r < 4; ++r) {
                float s = 0.f;
#pragma unroll
                for (int t = 0; t < 8; ++t) s += acc[rt][t][r] * acc[rt][t][r];
                s += __shfl_xor(s, 1);
                s += __shfl_xor(s, 2);
                s += __shfl_xor(s, 4);
                s += __shfl_xor(s, 8);
                if (l16 == 0) sq[wave][rt * 16 + quad * 4 + r] = s;
            }
        __syncthreads();
#pragma unroll
        for (int rt = 0; rt < 2; ++rt)
#pragma unroll
            for (int r = 0; r < 4; ++r) {
                int row = rt * 16 + quad * 4 + r;
                float tot = sq[0][row] + sq[1][row] + sq[2][row] + sq[3][row];
                inv[rt][r] = 1.0f / fmaxf(sqrtf(tot), 1e-12f);
            }
    }

#pragma unroll
    for (int rt = 0; rt < 2; ++rt)
#pragma unroll
        for (int t = 0; t < 8; ++t)
#pragma unroll
            for (int r = 0; r < 4; ++r) {
                const size_t o = (size_t)(m0 + rt * 16 + quad * 4 + r) * 512
                               + (e0 + t * 16 + l16);
                float val = acc[rt][t][r] * inv[rt][r];
                out[o] = val;
                if (outb) outb[o] = (bf16_t)val;
            }
}

// ---------------------------------------------------------------------------
// MaxSim v5: 32x32x16 MFMA, natural block mapping (q = n>>6, bp = n&63 keeps
// each XCD's te slice fixed & L2-resident). Block = (q, b-pair), 4 waves:
// wave = (bhat = w>>1, tt = w&1) -> b = 2bp+bhat, t rows tt*32..+31, ALL 7
// v-tiles -> acc[7] = 112 AGPR (uniform, no dead slots; + ~100 VGPR -> 2
// waves/SIMD). ve chunks (224 rows x 64 k) via global_load_lds, double-
// buffered, XOR-swizzled (phys seg = logical ^ (row&7)); one barrier/chunk.
// A/B: m|n = lane&31, k = (lane>>5)*8+j. C/D: col = lane&31,
// row = (reg&3) + 8*(reg>>2) + 4*(lane>>5).
// ---------------------------------------------------------------------------
__global__ __launch_bounds__(256) void maxsim32(
    const bf16_t* __restrict__ te,  // [128,64,512]
    const bf16_t* __restrict__ ve,  // [128,196,512]
    float* __restrict__ sim)        // [128,128] (b major)
{
    const int tid  = threadIdx.x;
    const int wave = tid >> 6;
    const int lane = tid & 63;
    const int l32  = lane & 31;
    const int h    = lane >> 5;
    const int bhat = wave >> 1;
    const int tt   = wave & 1;

    const int n  = blockIdx.x;
    const int q  = n >> 6;
    const int bp = n & 63;
    const int b  = bp * 2 + bhat;

    __shared__ bf16_t vs[2][224 * 64];      // 2 x 28672 B
    __shared__ float  tmax_s[2][64];        // [bhat][t]  (tt waves: disjoint rows)
    __shared__ float  vmax_s[2][2][224];    // [bhat][tt][v]

    f32x16 acc[7];
#pragma unroll
    for (int vt = 0; vt < 7; ++vt)
#pragma unroll
        for (int r = 0; r < 16; ++r) acc[vt][r] = 0.f;

    auto issue = [&](int buf, int c) {
        for (int g = wave; g < 28; g += 4) {      // 8 rows per DMA instr
            int r   = g * 8 + (lane >> 3);
            int sr  = r < 196 ? r : 195;          // clamp; excluded in reductions
            int seg = (lane & 7) ^ (lane >> 3);   // logical seg for phys slot l&7
            gload_lds16(ve + ((size_t)q * 196 + sr) * 512 + c * 64 + seg * 8,
                        &vs[buf][g * 512]);
        }
    };

    const size_t tbase = ((size_t)b * 64 + tt * 32 + l32) * 512;

    issue(0, 0);
#pragma unroll
    for (int c = 0; c < 8; ++c) {
        __syncthreads();                          // buf c&1 DMA complete
        if (c < 7) issue((c + 1) & 1, c + 1);
        bf16x8 a[4];
#pragma unroll
        for (int ks = 0; ks < 4; ++ks)
            a[ks] = *reinterpret_cast<const bf16x8*>(
                te + tbase + c * 64 + ks * 16 + h * 8);
        const int buf = c & 1;
#pragma unroll
        for (int ks = 0; ks < 4; ++ks)
#pragma unroll
            for (int vt = 0; vt < 7; ++vt) {
                int row  = vt * 32 + l32;
                int phys = (ks * 2 + h) ^ (row & 7);
                bf16x8 bv = *reinterpret_cast<const bf16x8*>(
                    &vs[buf][row * 64 + phys * 8]);
                acc[vt] = MFMA32(a[ks], bv, acc[vt]);
            }
    }

    // ---- reductions. D map: col v = vt*32 + l32,
    //      row t(within tt-tile) = (reg&3) + 8*(reg>>2) + 4*h.
    // t2v partial: per t-row max over all v (this wave covers every v for its rows)
#pragma unroll
    for (int reg = 0; reg < 16; ++reg) {
        float m = acc[0][reg];
#pragma unroll
        for (int vt = 1; vt < 6; ++vt) m = fmaxf(m, acc[vt][reg]);
        if (l32 < 4) m = fmaxf(m, acc[6][reg]);   // tile 6: cols 192..195 valid
        m = fmaxf(m, __shfl_xor(m, 1));
        m = fmaxf(m, __shfl_xor(m, 2));
        m = fmaxf(m, __shfl_xor(m, 4));
        m = fmaxf(m, __shfl_xor(m, 8));
        m = fmaxf(m, __shfl_xor(m, 16));
        if (l32 == 0) {
            int row = tt * 32 + (reg & 3) + 8 * (reg >> 2) + 4 * h;
            tmax_s[bhat][row] = m;
        }
    }
    // v2t partial: per v-col max over this wave's 32 t rows
#pragma unroll
    for (int vt = 0; vt < 7; ++vt) {
        float m = acc[vt][0];
#pragma unroll
        for (int reg = 1; reg < 16; ++reg) m = fmaxf(m, acc[vt][reg]);
        m = fmaxf(m, __shfl_xor(m, 32));          // combine h halves
        if (h == 0) vmax_s[bhat][tt][vt * 32 + l32] = m;
    }
    __syncthreads();

    if (wave == 0) {
        float t0 = tmax_s[0][lane];               // 64 lanes = 64 t rows
        float t1 = tmax_s[1][lane];
        float c0 = 0.f, c1 = 0.f;
        for (int v = lane; v < 196; v += 64) {
            c0 += fmaxf(vmax_s[0][0][v], vmax_s[0][1][v]);
            c1 += fmaxf(vmax_s[1][0][v], vmax_s[1][1][v]);
        }
#pragma unroll
        for (int mk = 1; mk <= 32; mk <<= 1) {
            t0 += __shfl_xor(t0, mk);
            t1 += __shfl_xor(t1, mk);
            c0 += __shfl_xor(c0, mk);
            c1 += __shfl_xor(c1, mk);
        }
        if (lane == 0) {
            sim[(size_t)(bp * 2 + 0) * 128 + q] = 0.5f * (t0 * (1.0f / 196.0f) + c0 * (1.0f / 64.0f));
            sim[(size_t)(bp * 2 + 1) * 128 + q] = 0.5f * (t1 * (1.0f / 196.0f) + c1 * (1.0f / 64.0f));
        }
    }
}

// ---------------------------------------------------------------------------
// Fallback projection (f32 weights, 16-row blocks) — used only if ws too small
// ---------------------------------------------------------------------------
__global__ __launch_bounds__(256) void proj_fb(
    const float* __restrict__ A, const float* __restrict__ Wf,
    const float* __restrict__ bias, float* __restrict__ out, int do_l2)
{
    const int tid  = threadIdx.x;
    const int wave = tid >> 6;
    const int lane = tid & 63;
    const int l16  = lane & 15;
    const int quad = lane >> 4;
    const int m0   = blockIdx.x * 16;
    const int e0   = wave * 128;

    f32x4 acc[8];
#pragma unroll
    for (int t = 0; t < 8; ++t) acc[t] = (f32x4){0.f, 0.f, 0.f, 0.f};
    const float* arow = A + (size_t)(m0 + l16) * 768 + quad * 8;
    for (int k0 = 0; k0 < 768; k0 += 32) {
        bf16x8 af = cvt8(arow + k0);
#pragma unroll
        for (int t = 0; t < 8; ++t) {
            bf16x8 wv = cvt8(Wf + (size_t)(e0 + t * 16 + l16) * 768 + quad * 8 + k0);
            acc[t] = MFMA16(af, wv, acc[t]);
        }
    }
#pragma unroll
    for (int t = 0; t < 8; ++t) {
        float bv = bias[e0 + t * 16 + l16];
#pragma unroll
        for (int r = 0; r < 4; ++r) acc[t][r] += bv;
    }
    float inv[4] = {1.f, 1.f, 1.f, 1.f};
    __shared__ float sq[4][16];
    if (do_l2) {
#pragma unroll
        for (int r = 0; r < 4; ++r) {
            float s = 0.f;
#pragma unroll
            for (int t = 0; t < 8; ++t) s += acc[t][r] * acc[t][r];
            s += __shfl_xor(s, 1); s += __shfl_xor(s, 2);
            s += __shfl_xor(s, 4); s += __shfl_xor(s, 8);
            if (l16 == 0) sq[wave][quad * 4 + r] = s;
        }
        __syncthreads();
#pragma unroll
        for (int r = 0; r < 4; ++r) {
            float tot = sq[0][quad * 4 + r] + sq[1][quad * 4 + r]
                      + sq[2][quad * 4 + r] + sq[3][quad * 4 + r];
            inv[r] = 1.0f / fmaxf(sqrtf(tot), 1e-12f);
        }
    }
#pragma unroll
    for (int t = 0; t < 8; ++t)
#pragma unroll
        for (int r = 0; r < 4; ++r)
            out[(size_t)(m0 + quad * 4 + r) * 512 + (e0 + t * 16 + l16)] =
                acc[t][r] * inv[r];
}

// ---------------------------------------------------------------------------
// Fallback maxsim (f32 operands from d_out, 16x16 path) — ws-too-small only
// ---------------------------------------------------------------------------
__global__ __launch_bounds__(256) void maxsim_fb(
    const float* __restrict__ te, const float* __restrict__ ve,
    float* __restrict__ sim)
{
    const int tid  = threadIdx.x;
    const int wave = tid >> 6;
    const int lane = tid & 63;
    const int l16  = lane & 15;
    const int quad = lane >> 4;
    const int q    = blockIdx.x >> 6;
    const int bp   = blockIdx.x & 63;

    __shared__ bf16_t vsl[208 * 72];
    __shared__ float  maxt_s[2][4][208];
    __shared__ float  t2v_part[2][4];

    f32x4 acc0[13], acc1[13];
#pragma unroll
    for (int vt = 0; vt < 13; ++vt) {
        acc0[vt] = (f32x4){0.f, 0.f, 0.f, 0.f};
        acc1[vt] = (f32x4){0.f, 0.f, 0.f, 0.f};
    }
    const size_t toff0 = ((size_t)(bp * 2) * 64 + wave * 16 + l16) * 512 + quad * 8;
    const size_t toff1 = toff0 + (size_t)64 * 512;

    for (int k0 = 0; k0 < 512; k0 += 64) {
        __syncthreads();
        for (int s = tid; s < 416; s += 256) {
            const int row  = s >> 1;
            const int half = s & 1;
            const int vsrc = row < 196 ? row : 195;
            bf16x8 tmp[4];
            const size_t goff = ((size_t)q * 196 + vsrc) * 512 + k0 + half * 32;
#pragma unroll
            for (int j = 0; j < 4; ++j) tmp[j] = cvt8(ve + goff + j * 8);
            bf16_t* dst = &vsl[row * 72 + half * 32];
#pragma unroll
            for (int j = 0; j < 4; ++j)
                *reinterpret_cast<bf16x8*>(dst + j * 8) = tmp[j];
        }
        __syncthreads();
#pragma unroll
        for (int ks = 0; ks < 2; ++ks) {
            bf16x8 a0 = cvt8(te + toff0 + k0 + ks * 32);
            bf16x8 a1 = cvt8(te + toff1 + k0 + ks * 32);
#pragma unroll
            for (int vt = 0; vt < 13; ++vt) {
                bf16x8 bv = *reinterpret_cast<const bf16x8*>(
                    &vsl[(vt * 16 + l16) * 72 + ks * 32 + quad * 8]);
                acc0[vt] = MFMA16(a0, bv, acc0[vt]);
                acc1[vt] = MFMA16(a1, bv, acc1[vt]);
            }
        }
    }
#pragma unroll
    for (int bi = 0; bi < 2; ++bi) {
        const f32x4* acc = bi ? acc1 : acc0;
        float sum_maxv = 0.f;
#pragma unroll
        for (int r = 0; r < 4; ++r) {
            float m = -3.0e38f;
#pragma unroll
            for (int vt = 0; vt < 13; ++vt) {
                int v = vt * 16 + l16;
                if (v < 196) m = fmaxf(m, acc[vt][r]);
            }
            m = fmaxf(m, __shfl_xor(m, 1));
            m = fmaxf(m, __shfl_xor(m, 2));
            m = fmaxf(m, __shfl_xor(m, 4));
            m = fmaxf(m, __shfl_xor(m, 8));
            sum_maxv += m;
        }
        sum_maxv += __shfl_xor(sum_maxv, 16);
        sum_maxv += __shfl_xor(sum_maxv, 32);
        if (lane == 0) t2v_part[bi][wave] = sum_maxv;
#pragma unroll
        for (int vt = 0; vt < 13; ++vt) {
            float m = fmaxf(fmaxf(acc[vt][0], acc[vt][1]),
                            fmaxf(acc[vt][2], acc[vt][3]));
            m = fmaxf(m, __shfl_xor(m, 16));
            m = fmaxf(m, __shfl_xor(m, 32));
            if (lane < 16) maxt_s[bi][wave][vt * 16 + l16] = m;
        }
    }
    __syncthreads();
    if (wave == 0) {
#pragma unroll
        for (int bi = 0; bi < 2; ++bi) {
            float s_row = t2v_part[bi][0] + t2v_part[bi][1]
                        + t2v_part[bi][2] + t2v_part[bi][3];
            float s_col = 0.f;
            for (int v = lane; v < 196; v += 64) {
                float m = fmaxf(fmaxf(maxt_s[bi][0][v], maxt_s[bi][1][v]),
                                fmaxf(maxt_s[bi][2][v], maxt_s[bi][3][v]));
                s_col += m;
            }
            s_col += __shfl_xor(s_col, 1);
            s_col += __shfl_xor(s_col, 2);
            s_col += __shfl_xor(s_col, 4);
            s_col += __shfl_xor(s_col, 8);
            s_col += __shfl_xor(s_col, 16);
            s_col += __shfl_xor(s_col, 32);
            if (lane == 0)
                sim[(size_t)(bp * 2 + bi) * 128 + q] =
                    0.5f * (s_row * (1.0f / 196.0f) + s_col * (1.0f / 64.0f));
        }
    }
}

// ---------------------------------------------------------------------------
// text_mask[b,t] = (t < len[b]); int64-vs-int32 auto-detect (lengths 1..64).
// ---------------------------------------------------------------------------
__global__ void mask_kernel(const int* __restrict__ len, float* __restrict__ mask)
{
    int i = blockIdx.x * 256 + threadIdx.x;
    int is64 = (len[1] == 0) ? 1 : 0;
    if (i < 128 * 64) {
        int b = i >> 6;
        int t = i & 63;
        int L = is64 ? len[2 * b] : len[b];
        mask[i] = (t < L) ? 1.0f : 0.0f;
    }
}

extern "C" void kernel_launch(void* const* d_in, const int* in_sizes, int n_in,
                              void* d_out, int out_size, void* d_ws, size_t ws_size,
                              hipStream_t stream)
{
    int idx[13] = {0, 1, 2, 3, 4, 5, 6, 7, 8, 9, 10, 11, 12};
    if (in_sizes && n_in >= 13) {
        bool dict = (in_sizes[2] == 19267584) && (in_sizes[4] == 393216);
        if (!dict) {
            static const int alpha_sizes[13] = {393216, 393216, 393216, 393216,
                                                512, 512, 512, 512, 128,
                                                98304, 6291456, 98304, 19267584};
            bool alpha = true;
            for (int i = 0; i < 13; ++i)
                if (in_sizes[i] != alpha_sizes[i]) { alpha = false; break; }
            if (alpha) {
                const int m[13] = {11, 9, 12, 10, 2, 6, 0, 4, 3, 7, 1, 5, 8};
                for (int i = 0; i < 13; ++i) idx[i] = m[i];
            }
        }
    }

    const float* visual_cls     = (const float*)d_in[idx[0]];
    const float* textual_cls    = (const float*)d_in[idx[1]];
    const float* visual_tokens  = (const float*)d_in[idx[2]];
    const float* textual_tokens = (const float*)d_in[idx[3]];
    const float* Wv_cls = (const float*)d_in[idx[4]];
    const float* bv_cls = (const float*)d_in[idx[5]];
    const float* Wt_cls = (const float*)d_in[idx[6]];
    const float* bt_cls = (const float*)d_in[idx[7]];
    const float* Wv_tok = (const float*)d_in[idx[8]];
    const float* bv_tok = (const float*)d_in[idx[9]];
    const float* Wt_tok = (const float*)d_in[idx[10]];
    const float* bt_tok = (const float*)d_in[idx[11]];
    const int*   text_length = (const int*)d_in[idx[12]];

    float* out    = (float*)d_out;
    float* o_vcls = out;
    float* o_tcls = out + 65536;
    float* o_ve   = out + 131072;
    float* o_te   = out + 12976128;
    float* o_mask = out + 17170432;
    float* o_sim  = out + 17178624;

    const size_t NVE = 12845056;
    const size_t NTE = 4194304;
    const bool ws_big = ws_size >= (4 * (size_t)WN + NVE + NTE) * 2;

    bf16_t* w_all = (bf16_t*)d_ws;            // 4 weights contiguous
    bf16_t* b_ve  = w_all + 4 * (size_t)WN;
    bf16_t* b_te  = b_ve + NVE;

    dim3 blk(256);
    if (ws_big) {
        cvt_w4<<<(4 * WN / 4 + 255) / 256, blk, 0, stream>>>(Wv_cls, Wt_cls, Wv_tok, Wt_tok, w_all);
        proj_all<<<1048, blk, 0, stream>>>(visual_tokens, textual_tokens,
                                           visual_cls, textual_cls, w_all,
                                           bv_cls, bt_cls, bv_tok, bt_tok,
                                           out, b_ve, b_te);
        mask_kernel<<<32, blk, 0, stream>>>(text_length, o_mask);
        maxsim32<<<128 * 64, blk, 0, stream>>>(b_te, b_ve, o_sim);
    } else {
        proj_fb<<<8,    blk, 0, stream>>>(visual_cls,     Wv_cls, bv_cls, o_vcls, 0);
        proj_fb<<<8,    blk, 0, stream>>>(textual_cls,    Wt_cls, bt_cls, o_tcls, 0);
        proj_fb<<<1568, blk, 0, stream>>>(visual_tokens,  Wv_tok, bv_tok, o_ve, 1);
        proj_fb<<<512,  blk, 0, stream>>>(textual_tokens, Wt_tok, bt_tok, o_te, 1);
        mask_kernel<<<32, blk, 0, stream>>>(text_length, o_mask);
        maxsim_fb<<<128 * 64, blk, 0, stream>>>(o_te, o_ve, o_sim);
    }
}